// Round 8
// baseline (103.242 us; speedup 1.0000x reference)
//
#include <hip/hip_runtime.h>
#include <hip/hip_bf16.h>
#include <stdint.h>

#define N_NODES 100000
#define C 128
#define NET 7
#define E_EDGES 700000
#define S_SLOTS (N_NODES * NET)
#define BM 64
#define NB_CVTX 6250            // 100000*128/8/256
#define NB_CVTW 56              // 7*8*4*64/256
#define NB_PAIRS ((S_SLOTS + 255) / 256)

typedef __attribute__((ext_vector_type(8))) short short8;
typedef __attribute__((ext_vector_type(4))) float f32x4;
typedef __attribute__((ext_vector_type(4))) unsigned int uint4v;

// ---------- threefry2x32 (JAX), verified round 2 ----------
struct TF2 { uint32_t a, b; };

__host__ __device__ constexpr uint32_t rotl32c(uint32_t v, int r) {
    return (v << r) | (v >> (32 - r));
}

__host__ __device__ constexpr TF2 threefry2x32(uint32_t k0, uint32_t k1,
                                               uint32_t x0, uint32_t x1) {
    const uint32_t ks0 = k0, ks1 = k1, ks2 = 0x1BD11BDAu ^ k0 ^ k1;
    x0 += ks0; x1 += ks1;
#define RND(r) { x0 += x1; x1 = rotl32c(x1, (r)); x1 ^= x0; }
    RND(13) RND(15) RND(26) RND(6)
    x0 += ks1; x1 += ks2 + 1u;
    RND(17) RND(29) RND(16) RND(24)
    x0 += ks2; x1 += ks0 + 2u;
    RND(13) RND(15) RND(26) RND(6)
    x0 += ks0; x1 += ks1 + 3u;
    RND(17) RND(29) RND(16) RND(24)
    x0 += ks1; x1 += ks2 + 4u;
    RND(13) RND(15) RND(26) RND(6)
    x0 += ks2; x1 += ks0 + 5u;
#undef RND
    return TF2{x0, x1};
}

constexpr TF2 K2 = threefry2x32(0u, 42u, 0u, 1u);  // split(key(42),2)[1]

__device__ __forceinline__ uint32_t jax_bits32(uint32_t f) {
    TF2 o = threefry2x32(K2.a, K2.b, 0u, f);
    return o.a ^ o.b;
}

__device__ __forceinline__ unsigned short f2bf(float f) {
    uint32_t u = __float_as_uint(f);
    u += 0x7fffu + ((u >> 16) & 1u);
    return (unsigned short)(u >> 16);
}

__device__ __forceinline__ int lbound(const int* __restrict__ idx, int v) {
    int l = 0, r = E_EDGES;
    while (l < r) { int m = (l + r) >> 1; if (idx[m] < v) l = m + 1; else r = m; }
    return l;
}

// ---------- prep: cvt_x || cvt_w(frag-major, x0.5) || pairs(shared binary search) ----------
__global__ __launch_bounds__(256) void prep(const float* __restrict__ x,
                                            const int* __restrict__ col,
                                            const int* __restrict__ idx,
                                            const float* __restrict__ W,
                                            unsigned short* __restrict__ xb,
                                            unsigned short* __restrict__ Wf,
                                            int2* __restrict__ pairs,
                                            char* __restrict__ zp) {
    const int b = blockIdx.x;
    if (b < NB_CVTX) {
        if (b == 0 && threadIdx.x < 16) {           // zero page for empty rows
            uint4v z = {0u, 0u, 0u, 0u};
            ((uint4v*)zp)[threadIdx.x] = z;
        }
        int i = b * 256 + threadIdx.x;
        const float4* src = (const float4*)x + (size_t)i * 2;
        float4 a = src[0], v = src[1];
        union { unsigned short u[8]; uint4v q; } o;
        o.u[0] = f2bf(a.x); o.u[1] = f2bf(a.y); o.u[2] = f2bf(a.z); o.u[3] = f2bf(a.w);
        o.u[4] = f2bf(v.x); o.u[5] = f2bf(v.y); o.u[6] = f2bf(v.z); o.u[7] = f2bf(v.w);
        ((uint4v*)xb)[i] = o.q;
    } else if (b < NB_CVTX + NB_CVTW) {
        // Wf[((et*8+n16)*4+ks)*512 + lane*8 + j] = 0.5 * W  (frag-major, verified round 4)
        int t = (b - NB_CVTX) * 256 + threadIdx.x;   // < 14336
        int l = t & 63, ks = (t >> 6) & 3, n16 = (t >> 8) & 7, et = t >> 11;
        int n = n16 * 16 + (l & 15);
        int k0 = ks * 32 + (l >> 4) * 8;
        union { unsigned short u[8]; uint4v q; } o;
#pragma unroll
        for (int j = 0; j < 8; j++)
            o.u[j] = f2bf(0.5f * W[(size_t)(et * 128 + k0 + j) * 128 + n]);
        ((uint4v*)Wf)[t] = o.q;
    } else {
        int s = (b - NB_CVTX - NB_CVTW) * 256 + threadIdx.x;
        bool valid = s < S_SLOTS;
        int lo = E_EDGES;
        if (valid) lo = lbound(idx, s);              // every valid thread searches (neighbor needs it)
        int hi = __shfl_down(lo, 1);
        if ((threadIdx.x & 63) == 63 && valid)
            hi = (s + 1 < S_SLOTS) ? lbound(idx, s + 1) : E_EDGES;
        if (!valid) return;
        if (s % NET == NET - 1) {                    // self slot: (x+x)*0.5W = x
            int node = s / NET;
            pairs[s] = make_int2(node, node);
            return;
        }
        int cnt = hi - lo;
        if (cnt <= 0) { pairs[s] = make_int2(-1, -1); return; }
        uint32_t b0 = jax_bits32((uint32_t)s * 2u + 0u) & 0x3FFFFFFFu;
        uint32_t b1 = jax_bits32((uint32_t)s * 2u + 1u) & 0x3FFFFFFFu;
        pairs[s] = make_int2(col[lo + (int)(b0 % (uint32_t)cnt)],
                             col[lo + (int)(b1 % (uint32_t)cnt)]);
    }
}

// ---------- fused: A1/A2 two-tile staging via global_load_lds + bf16 MFMA ----------
// BM=64 x 128 tile, 512 thr = 8 waves; wave w computes rows nb..nb+63 x cols w*16..+15
// (fm=4, fn=1 -> B load 4 KB/wave/et, no inter-wave duplication).
// LDS [2 buf][2 tiles][64 rows][256 B]; XOR-swizzle byte^=((row&7)<<4) applied on the
// GLOBAL source address (LDS dest linear) and on the read side. B double-buffered in regs.
__global__ __launch_bounds__(512, 4) void fused_mfma(const unsigned short* __restrict__ xb,
                                                     const int2* __restrict__ pairs,
                                                     const unsigned short* __restrict__ Wf,
                                                     const char* __restrict__ zp,
                                                     float* __restrict__ out) {
    __shared__ unsigned short Alds[2 * 2 * BM * C];  // 64 KiB
    const int tid  = threadIdx.x;
    const int nb   = blockIdx.x * BM;
    const int wave = tid >> 6, lane = tid & 63;
    const int lr   = lane & 15, lg = lane >> 4;
    const int sw   = wave & 3,  tsel = wave >> 2;    // staging: row-group, tile select
    const int lg4  = lane >> 4;
    const int scol = (lane & 15) * 16;
    const char* xbc = (const char*)xb;

    // staging pair indices (rows fixed per thread across et)
    int pidx[4];
#pragma unroll
    for (int J = 0; J < 4; J++) {
        int r = nb + sw * 16 + J * 4 + lg4;
        pidx[J] = (r < N_NODES) ? r * NET : -1;
    }
    int2 pjn[4];
#define LOADPJ(ET) { _Pragma("unroll") \
    for (int J = 0; J < 4; J++) \
        pjn[J] = (pidx[J] < 0) ? make_int2(-1, -1) : pairs[pidx[J] + (ET)]; }

#define STAGE1(J, LB) { \
    int2 p_ = pjn[J]; \
    const char* s_ = (p_.x < 0) ? zp \
                   : (xbc + ((size_t)(tsel ? p_.y : p_.x) << 8)); \
    const char* g_ = s_ + (scol ^ ((((J) * 4 + lg4) & 7) << 4)); \
    __builtin_amdgcn_global_load_lds((const __attribute__((address_space(1))) void*)g_, \
        (__attribute__((address_space(3))) void*)((LB) + (J) * 1024), 16, 0, 0); }

#define STAGE4(BUFOFF) { \
    char* lb_ = (char*)Alds + (BUFOFF) + tsel * 16384 + sw * 4096; \
    STAGE1(0, lb_) STAGE1(1, lb_) STAGE1(2, lb_) STAGE1(3, lb_) }

// B slice for this wave (cols wave*16..+15), k-step ks of et
#define LOADB(DST, ET) { _Pragma("unroll") \
    for (int ks = 0; ks < 4; ks++) \
        (DST)[ks] = *(const short8*)(Wf \
            + (size_t)((((ET) * 8 + wave) * 4 + ks) * 512) + lane * 8); }

    // A-frag read column offsets (lane-dependent, et-invariant)
    const int rsw = (lr & 7) << 4;
    int aoffk[4];
#pragma unroll
    for (int ks = 0; ks < 4; ks++)
        aoffk[ks] = lr * 256 + ((ks * 64 + lg * 16) ^ rsw);

    f32x4 acc[4];
#pragma unroll
    for (int i = 0; i < 4; i++) acc[i] = (f32x4)0.f;

    short8 bfr[2][4];

    // prologue: stage et=0 into buf 0, preload B(0)
    LOADPJ(0)
    STAGE4(0)
    LOADB(bfr[0], 0)
    LOADPJ(1)
    __syncthreads();   // vmcnt(0) before barrier drains staging + B loads

#pragma unroll
    for (int et = 0; et < NET; ++et) {
        const int cur = et & 1;
        const int curoff = cur * 32768;

        // issue next et's staging + B prefetch (drained by this iteration's barrier)
        if (et + 1 < NET) {
            STAGE4(curoff ^ 32768)
            LOADB(bfr[cur ^ 1], et + 1)
            if (et + 2 < NET) LOADPJ(et + 2)
        }

        // MFMA: 4 k-steps x 4 fm x 2 tiles, B from regs (preloaded)
#pragma unroll
        for (int ks = 0; ks < 4; ks++) {
            const char* ab = (const char*)Alds + curoff + aoffk[ks];
            short8 b_ = bfr[cur][ks];
#pragma unroll
            for (int fm = 0; fm < 4; fm++) {
                short8 a0 = *(const short8*)(ab + fm * 4096);           // tile0
                short8 a1 = *(const short8*)(ab + 16384 + fm * 4096);   // tile1
                acc[fm] = __builtin_amdgcn_mfma_f32_16x16x32_bf16(a0, b_, acc[fm], 0, 0, 0);
                acc[fm] = __builtin_amdgcn_mfma_f32_16x16x32_bf16(a1, b_, acc[fm], 0, 0, 0);
            }
        }

        __syncthreads();
    }

    // epilogue: D layout col=lane&15, row=(lane>>4)*4+reg
#pragma unroll
    for (int fm = 0; fm < 4; fm++) {
        int row0 = nb + fm * 16 + lg * 4;
        int colo = wave * 16 + lr;
#pragma unroll
        for (int j = 0; j < 4; j++)
            if (row0 + j < N_NODES)
                out[(size_t)(row0 + j) * C + colo] = acc[fm][j];
    }
#undef LOADPJ
#undef STAGE1
#undef STAGE4
#undef LOADB
}

extern "C" void kernel_launch(void* const* d_in, const int* in_sizes, int n_in,
                              void* d_out, int out_size, void* d_ws, size_t ws_size,
                              hipStream_t stream) {
    const float* x   = (const float*)d_in[0];
    const int*   col = (const int*)d_in[1];
    const int*   idx = (const int*)d_in[2];
    const float* W   = (const float*)d_in[3];
    float* out = (float*)d_out;

    char* zp           = (char*)d_ws;                               // 256 B zero page
    int2* pairs        = (int2*)(zp + 256);                         // 5.6 MB
    unsigned short* xb = (unsigned short*)((char*)pairs + (size_t)S_SLOTS * 8);  // 25.6 MB
    unsigned short* Wf = xb + (size_t)N_NODES * C;                  // 229 KB

    prep<<<NB_CVTX + NB_CVTW + NB_PAIRS, 256, 0, stream>>>(x, col, idx, W, xb, Wf, pairs, zp);
    fused_mfma<<<(N_NODES + BM - 1) / BM, 512, 0, stream>>>(xb, pairs, Wf, zp, out);
}

// Round 9
// 92.587 us; speedup vs baseline: 1.1151x; 1.1151x over previous
//
#include <hip/hip_runtime.h>
#include <hip/hip_bf16.h>
#include <stdint.h>

#define N_NODES 100000
#define C 128
#define NET 7
#define E_EDGES 700000
#define S_SLOTS (N_NODES * NET)
#define BM 64
#define NB_CVTX 6250            // 100000*128/8/256
#define NB_CVTW 56              // 7*8*4*64/256
#define NB_PAIRS ((S_SLOTS + 255) / 256)

typedef __attribute__((ext_vector_type(8))) short short8;
typedef __attribute__((ext_vector_type(4))) float f32x4;
typedef __attribute__((ext_vector_type(4))) unsigned int uint4v;

// ---------- threefry2x32 (JAX), verified round 2 ----------
struct TF2 { uint32_t a, b; };

__host__ __device__ constexpr uint32_t rotl32c(uint32_t v, int r) {
    return (v << r) | (v >> (32 - r));
}

__host__ __device__ constexpr TF2 threefry2x32(uint32_t k0, uint32_t k1,
                                               uint32_t x0, uint32_t x1) {
    const uint32_t ks0 = k0, ks1 = k1, ks2 = 0x1BD11BDAu ^ k0 ^ k1;
    x0 += ks0; x1 += ks1;
#define RND(r) { x0 += x1; x1 = rotl32c(x1, (r)); x1 ^= x0; }
    RND(13) RND(15) RND(26) RND(6)
    x0 += ks1; x1 += ks2 + 1u;
    RND(17) RND(29) RND(16) RND(24)
    x0 += ks2; x1 += ks0 + 2u;
    RND(13) RND(15) RND(26) RND(6)
    x0 += ks0; x1 += ks1 + 3u;
    RND(17) RND(29) RND(16) RND(24)
    x0 += ks1; x1 += ks2 + 4u;
    RND(13) RND(15) RND(26) RND(6)
    x0 += ks2; x1 += ks0 + 5u;
#undef RND
    return TF2{x0, x1};
}

constexpr TF2 K2 = threefry2x32(0u, 42u, 0u, 1u);  // split(key(42),2)[1]

__device__ __forceinline__ uint32_t jax_bits32(uint32_t f) {
    TF2 o = threefry2x32(K2.a, K2.b, 0u, f);
    return o.a ^ o.b;
}

__device__ __forceinline__ unsigned short f2bf(float f) {
    uint32_t u = __float_as_uint(f);
    u += 0x7fffu + ((u >> 16) & 1u);
    return (unsigned short)(u >> 16);
}

// sum two packed-bf16 dwords -> packed bf16 (truncation pack; x0.5 folded into Wf)
__device__ __forceinline__ uint32_t sumpack(uint32_t a, uint32_t b) {
    float alo = __uint_as_float(a << 16);
    float ahi = __uint_as_float(a & 0xffff0000u);
    float blo = __uint_as_float(b << 16);
    float bhi = __uint_as_float(b & 0xffff0000u);
    return (__float_as_uint(ahi + bhi) & 0xffff0000u) | (__float_as_uint(alo + blo) >> 16);
}

__device__ __forceinline__ uint4v sumpack4(uint4v a, uint4v b) {
    uint4v o;
    o.x = sumpack(a.x, b.x); o.y = sumpack(a.y, b.y);
    o.z = sumpack(a.z, b.z); o.w = sumpack(a.w, b.w);
    return o;
}

__device__ __forceinline__ int lbound(const int* __restrict__ idx, int v) {
    int l = 0, r = E_EDGES;
    while (l < r) { int m = (l + r) >> 1; if (idx[m] < v) l = m + 1; else r = m; }
    return l;
}

// ---------- prep: cvt_x || cvt_w(frag-major, x0.5) || pairs(shared binary search) ----------
__global__ __launch_bounds__(256) void prep(const float* __restrict__ x,
                                            const int* __restrict__ col,
                                            const int* __restrict__ idx,
                                            const float* __restrict__ W,
                                            unsigned short* __restrict__ xb,
                                            unsigned short* __restrict__ Wf,
                                            int2* __restrict__ pairs) {
    const int b = blockIdx.x;
    if (b < NB_CVTX) {
        int i = b * 256 + threadIdx.x;
        const float4* src = (const float4*)x + (size_t)i * 2;
        float4 a = src[0], v = src[1];
        union { unsigned short u[8]; uint4v q; } o;
        o.u[0] = f2bf(a.x); o.u[1] = f2bf(a.y); o.u[2] = f2bf(a.z); o.u[3] = f2bf(a.w);
        o.u[4] = f2bf(v.x); o.u[5] = f2bf(v.y); o.u[6] = f2bf(v.z); o.u[7] = f2bf(v.w);
        ((uint4v*)xb)[i] = o.q;
    } else if (b < NB_CVTX + NB_CVTW) {
        // Wf[((et*8+n16)*4+ks)*512 + lane*8 + j] = 0.5 * W  (frag-major, verified round 4)
        int t = (b - NB_CVTX) * 256 + threadIdx.x;   // < 14336
        int l = t & 63, ks = (t >> 6) & 3, n16 = (t >> 8) & 7, et = t >> 11;
        int n = n16 * 16 + (l & 15);
        int k0 = ks * 32 + (l >> 4) * 8;
        union { unsigned short u[8]; uint4v q; } o;
#pragma unroll
        for (int j = 0; j < 8; j++)
            o.u[j] = f2bf(0.5f * W[(size_t)(et * 128 + k0 + j) * 128 + n]);
        ((uint4v*)Wf)[t] = o.q;
    } else {
        int s = (b - NB_CVTX - NB_CVTW) * 256 + threadIdx.x;
        bool valid = s < S_SLOTS;
        int lo = E_EDGES;
        if (valid) lo = lbound(idx, s);              // every valid thread searches (neighbor needs it)
        int hi = __shfl_down(lo, 1);
        if ((threadIdx.x & 63) == 63 && valid)
            hi = (s + 1 < S_SLOTS) ? lbound(idx, s + 1) : E_EDGES;
        if (!valid) return;
        if (s % NET == NET - 1) {                    // self slot: (x+x)*0.5W = x
            int node = s / NET;
            pairs[s] = make_int2(node, node);
            return;
        }
        int cnt = hi - lo;
        if (cnt <= 0) { pairs[s] = make_int2(-1, -1); return; }
        uint32_t b0 = jax_bits32((uint32_t)s * 2u + 0u) & 0x3FFFFFFFu;
        uint32_t b1 = jax_bits32((uint32_t)s * 2u + 1u) & 0x3FFFFFFFu;
        pairs[s] = make_int2(col[lo + (int)(b0 % (uint32_t)cnt)],
                             col[lo + (int)(b1 % (uint32_t)cnt)]);
    }
}

// ---------- fused: reg-staged summed A tile + bf16 MFMA, counted-vmcnt pipeline ----------
// BM=64 x 128 tile, 512 thr = 8 waves, grid 2x4 (each wave 32 rows x 32 cols; fm=2,fn=2).
// LDS: 2 x [64 rows][256 B] summed A tiles, XOR-swizzled chunk^=(row&7) on BOTH write
// and read (uniform 8 lanes/bank-group = 1024B floor, zero excess conflicts).
// Barrier = s_waitcnt lgkmcnt(0) + s_barrier ONLY: gather loads issued 2 phases ahead
// stay in flight across barriers (counted vmcnt, T3/T4).
__global__ __launch_bounds__(512, 4) void fused_mfma(const unsigned short* __restrict__ xb,
                                                     const int2* __restrict__ pairs,
                                                     const unsigned short* __restrict__ Wf,
                                                     float* __restrict__ out) {
    __shared__ unsigned char Alds[2][BM * 256];     // 32 KiB
    const int tid  = threadIdx.x;
    const int nb   = blockIdx.x * BM;
    const int wave = tid >> 6, lane = tid & 63;
    const int wr   = wave >> 2, wc = wave & 3;      // compute: rows wr*32, cols wc*32
    const int lr   = lane & 15, lg = lane >> 4;
    const char* xbc = (const char*)xb;

    // staging: thread t owns row t>>3, chunks c0=(t&7)*2, c0+1 (16B each)
    const int srow = tid >> 3;
    const int c0   = (tid & 7) * 2;
    const int arow = nb + srow;
    const int prow = (arow < N_NODES) ? arow * NET : -1;
    const int sa0  = srow * 256 + (((c0    ) ^ (srow & 7)) << 4);
    const int sa1  = srow * 256 + (((c0 | 1) ^ (srow & 7)) << 4);

    uint4v g0[2][2], g1[2][2];   // gather sets (parity), 2 chunks each
    int2 sp[2];

#define GLOAD(SET, PV) { \
    int2 p_ = (PV); \
    if (p_.x >= 0) { \
        const uint4v* s0_ = (const uint4v*)(xbc + ((size_t)p_.x << 8) + (c0 << 4)); \
        const uint4v* s1_ = (const uint4v*)(xbc + ((size_t)p_.y << 8) + (c0 << 4)); \
        g0[SET][0] = s0_[0]; g0[SET][1] = s0_[1]; \
        g1[SET][0] = s1_[0]; g1[SET][1] = s1_[1]; \
    } else { \
        uint4v z_ = {0u, 0u, 0u, 0u}; \
        g0[SET][0] = z_; g0[SET][1] = z_; g1[SET][0] = z_; g1[SET][1] = z_; } }

#define COMBINE(SET, BUF) { \
    uint4v v0_ = sumpack4(g0[SET][0], g1[SET][0]); \
    uint4v v1_ = sumpack4(g0[SET][1], g1[SET][1]); \
    *(uint4v*)(&Alds[BUF][sa0]) = v0_; \
    *(uint4v*)(&Alds[BUF][sa1]) = v1_; }

// B slice for this wave (cols wc*32 + fn*16), frag-major Wf (verified)
#define LOADB(ET) { _Pragma("unroll") \
    for (int fn_ = 0; fn_ < 2; fn_++) { _Pragma("unroll") \
        for (int ks_ = 0; ks_ < 4; ks_++) \
            bfr[fn_][ks_] = *(const short8*)(Wf \
                + (size_t)((((ET) * 8 + wc * 2 + fn_) * 4 + ks_) * 512) + lane * 8); } }

#define BARRIER() { \
    asm volatile("s_waitcnt lgkmcnt(0)" ::: "memory"); \
    __builtin_amdgcn_s_barrier(); \
    __builtin_amdgcn_sched_barrier(0); }

    f32x4 acc[2][2];
#pragma unroll
    for (int i = 0; i < 2; i++)
#pragma unroll
        for (int j = 0; j < 2; j++) acc[i][j] = (f32x4)0.f;

    short8 bfr[2][4];

    // prologue: stage et0 -> buf0; issue gathers for et1; prime sp with et2/et3
    GLOAD(0, (prow >= 0) ? pairs[prow + 0] : make_int2(-1, -1))
    GLOAD(1, (prow >= 0) ? pairs[prow + 1] : make_int2(-1, -1))
    LOADB(0)
    sp[0] = (prow >= 0) ? pairs[prow + 2] : make_int2(-1, -1);
    sp[1] = (prow >= 0) ? pairs[prow + 3] : make_int2(-1, -1);
    COMBINE(0, 0)
    BARRIER()

#pragma unroll
    for (int et = 0; et < NET; ++et) {
        const int cur = et & 1;

        // 1) issue gathers for et+2 (land ~2 phases later; never drained by barrier)
        if (et + 2 < NET) {
            GLOAD(cur, sp[cur])
            sp[cur] = (et + 4 < NET && prow >= 0) ? pairs[prow + et + 4]
                                                  : make_int2(-1, -1);
        }
        // 2) B for current et (L2-resident; hidden under combine+ds latency)
        if (et > 0) LOADB(et)

        // 3) combine et+1 (vmcnt waits only for its own gather set) -> buf[cur^1]
        if (et + 1 < NET) COMBINE(cur ^ 1, cur ^ 1)

        // 4) MFMA(et): 4 ks x {2 ds_read_b128, 2x2 mfma}
#pragma unroll
        for (int ks = 0; ks < 4; ks++) {
            const int coff = ((ks * 4 + lg) ^ (lr & 7)) << 4;
            short8 a0 = *(const short8*)(&Alds[cur][(wr * 32      + lr) * 256 + coff]);
            short8 a1 = *(const short8*)(&Alds[cur][(wr * 32 + 16 + lr) * 256 + coff]);
            acc[0][0] = __builtin_amdgcn_mfma_f32_16x16x32_bf16(a0, bfr[0][ks], acc[0][0], 0, 0, 0);
            acc[0][1] = __builtin_amdgcn_mfma_f32_16x16x32_bf16(a0, bfr[1][ks], acc[0][1], 0, 0, 0);
            acc[1][0] = __builtin_amdgcn_mfma_f32_16x16x32_bf16(a1, bfr[0][ks], acc[1][0], 0, 0, 0);
            acc[1][1] = __builtin_amdgcn_mfma_f32_16x16x32_bf16(a1, bfr[1][ks], acc[1][1], 0, 0, 0);
        }

        // 5) lgkmcnt-only barrier (ds_writes visible; gathers stay in flight)
        if (et + 1 < NET) BARRIER()
    }

    // epilogue: D layout col=lane&15, row=(lane>>4)*4+reg (verified)
#pragma unroll
    for (int fm = 0; fm < 2; fm++) {
        int row0 = nb + wr * 32 + fm * 16 + lg * 4;
#pragma unroll
        for (int fn = 0; fn < 2; fn++) {
            int colo = wc * 32 + fn * 16 + lr;
#pragma unroll
            for (int j = 0; j < 4; j++)
                if (row0 + j < N_NODES)
                    out[(size_t)(row0 + j) * C + colo] = acc[fm][fn][j];
        }
    }
#undef GLOAD
#undef COMBINE
#undef LOADB
#undef BARRIER
}

extern "C" void kernel_launch(void* const* d_in, const int* in_sizes, int n_in,
                              void* d_out, int out_size, void* d_ws, size_t ws_size,
                              hipStream_t stream) {
    const float* x   = (const float*)d_in[0];
    const int*   col = (const int*)d_in[1];
    const int*   idx = (const int*)d_in[2];
    const float* W   = (const float*)d_in[3];
    float* out = (float*)d_out;

    int2* pairs        = (int2*)d_ws;                               // 5.6 MB
    unsigned short* xb = (unsigned short*)((char*)pairs + (size_t)S_SLOTS * 8);  // 25.6 MB
    unsigned short* Wf = xb + (size_t)N_NODES * C;                  // 229 KB

    prep<<<NB_CVTX + NB_CVTW + NB_PAIRS, 256, 0, stream>>>(x, col, idx, W, xb, Wf, pairs);
    fused_mfma<<<(N_NODES + BM - 1) / BM, 512, 0, stream>>>(xb, pairs, Wf, out);
}

// Round 10
// 75.015 us; speedup vs baseline: 1.3763x; 1.2343x over previous
//
#include <hip/hip_runtime.h>
#include <hip/hip_bf16.h>
#include <stdint.h>

#define N_NODES 100000
#define C 128
#define NET 7
#define E_EDGES 700000
#define S_SLOTS (N_NODES * NET)
#define BM 64
#define NB_CVTX 6250            // 100000*128/8/256
#define NB_CVTW 56              // 7*8*4*64/256
#define NB_INIT ((S_SLOTS + 255) / 256)

typedef __attribute__((ext_vector_type(8))) short short8;
typedef __attribute__((ext_vector_type(4))) float f32x4;
typedef __attribute__((ext_vector_type(4))) unsigned int uint4v;

// ---------- threefry2x32 (JAX), verified round 2 ----------
struct TF2 { uint32_t a, b; };

__host__ __device__ constexpr uint32_t rotl32c(uint32_t v, int r) {
    return (v << r) | (v >> (32 - r));
}

__host__ __device__ constexpr TF2 threefry2x32(uint32_t k0, uint32_t k1,
                                               uint32_t x0, uint32_t x1) {
    const uint32_t ks0 = k0, ks1 = k1, ks2 = 0x1BD11BDAu ^ k0 ^ k1;
    x0 += ks0; x1 += ks1;
#define RND(r) { x0 += x1; x1 = rotl32c(x1, (r)); x1 ^= x0; }
    RND(13) RND(15) RND(26) RND(6)
    x0 += ks1; x1 += ks2 + 1u;
    RND(17) RND(29) RND(16) RND(24)
    x0 += ks2; x1 += ks0 + 2u;
    RND(13) RND(15) RND(26) RND(6)
    x0 += ks0; x1 += ks1 + 3u;
    RND(17) RND(29) RND(16) RND(24)
    x0 += ks1; x1 += ks2 + 4u;
    RND(13) RND(15) RND(26) RND(6)
    x0 += ks2; x1 += ks0 + 5u;
#undef RND
    return TF2{x0, x1};
}

constexpr TF2 K2 = threefry2x32(0u, 42u, 0u, 1u);  // split(key(42),2)[1]

__device__ __forceinline__ uint32_t jax_bits32(uint32_t f) {
    TF2 o = threefry2x32(K2.a, K2.b, 0u, f);
    return o.a ^ o.b;
}

__device__ __forceinline__ unsigned short f2bf(float f) {
    uint32_t u = __float_as_uint(f);
    u += 0x7fffu + ((u >> 16) & 1u);
    return (unsigned short)(u >> 16);
}

// sum two packed-bf16 dwords -> packed bf16 (truncation pack; x0.5 folded into Wf)
__device__ __forceinline__ uint32_t sumpack(uint32_t a, uint32_t b) {
    float alo = __uint_as_float(a << 16);
    float ahi = __uint_as_float(a & 0xffff0000u);
    float blo = __uint_as_float(b << 16);
    float bhi = __uint_as_float(b & 0xffff0000u);
    return (__float_as_uint(ahi + bhi) & 0xffff0000u) | (__float_as_uint(alo + blo) >> 16);
}

__device__ __forceinline__ uint4v sumpack4(uint4v a, uint4v b) {
    uint4v o;
    o.x = sumpack(a.x, b.x); o.y = sumpack(a.y, b.y);
    o.z = sumpack(a.z, b.z); o.w = sumpack(a.w, b.w);
    return o;
}

// ---------- prep1: cvt_x || cvt_w(frag-major, x0.5) || pairs init (self / empty) ----------
__global__ __launch_bounds__(256) void prep1(const float* __restrict__ x,
                                             const float* __restrict__ W,
                                             unsigned short* __restrict__ xb,
                                             unsigned short* __restrict__ Wf,
                                             int2* __restrict__ pairs) {
    const int b = blockIdx.x;
    if (b < NB_CVTX) {
        int i = b * 256 + threadIdx.x;
        const float4* src = (const float4*)x + (size_t)i * 2;
        float4 a = src[0], v = src[1];
        union { unsigned short u[8]; uint4v q; } o;
        o.u[0] = f2bf(a.x); o.u[1] = f2bf(a.y); o.u[2] = f2bf(a.z); o.u[3] = f2bf(a.w);
        o.u[4] = f2bf(v.x); o.u[5] = f2bf(v.y); o.u[6] = f2bf(v.z); o.u[7] = f2bf(v.w);
        ((uint4v*)xb)[i] = o.q;
    } else if (b < NB_CVTX + NB_CVTW) {
        // Wf[((et*8+n16)*4+ks)*512 + lane*8 + j] = 0.5 * W  (frag-major, verified round 4)
        int t = (b - NB_CVTX) * 256 + threadIdx.x;   // < 14336
        int l = t & 63, ks = (t >> 6) & 3, n16 = (t >> 8) & 7, et = t >> 11;
        int n = n16 * 16 + (l & 15);
        int k0 = ks * 32 + (l >> 4) * 8;
        union { unsigned short u[8]; uint4v q; } o;
#pragma unroll
        for (int j = 0; j < 8; j++)
            o.u[j] = f2bf(0.5f * W[(size_t)(et * 128 + k0 + j) * 128 + n]);
        ((uint4v*)Wf)[t] = o.q;
    } else {
        int s = (b - NB_CVTX - NB_CVTW) * 256 + threadIdx.x;
        if (s >= S_SLOTS) return;
        int node = s / NET;
        pairs[s] = (s - node * NET == NET - 1) ? make_int2(node, node)   // self: (x+x)*0.5W
                                               : make_int2(-1, -1);      // empty default
    }
}

// ---------- prep2: run-scan over sorted edges -> sampled pairs ----------
__global__ __launch_bounds__(256) void prep2(const int* __restrict__ idx,
                                             const int* __restrict__ col,
                                             int2* __restrict__ pairs) {
    int e = blockIdx.x * 256 + threadIdx.x;
    if (e >= E_EDGES) return;
    int s = idx[e];
    if (e > 0 && idx[e - 1] == s) return;       // not a run start
    int len = 1;
    while (e + len < E_EDGES && idx[e + len] == s) ++len;
    if (s % NET == NET - 1) return;             // self slot: pre-initialized
    uint32_t b0 = jax_bits32((uint32_t)s * 2u + 0u) & 0x3FFFFFFFu;
    uint32_t b1 = jax_bits32((uint32_t)s * 2u + 1u) & 0x3FFFFFFFu;
    pairs[s] = make_int2(col[e + (int)(b0 % (uint32_t)len)],
                         col[e + (int)(b1 % (uint32_t)len)]);
}

// ---------- fused: reg-staged summed A tile + bf16 MFMA, in-order-aware pipeline ----------
// BM=64 x 128 tile, 512 thr = 8 waves; wave w computes ALL 64 rows x cols w*16..+15
// (fm=4, fn=1 -> zero B duplication across waves).
// VMEM queue discipline (vmcnt returns IN ORDER): per iteration issue
//   [B(et+1)] [gathers(et+3)] ... so the MFMA wait for B(et) (issued last iter, oldest)
// is vmcnt(12) and NEVER drains in-flight gathers; combine consumes a gather set
// issued 2 iterations earlier. Barrier = lgkmcnt(0) + s_barrier only.
// LDS: 2 x [64 rows][256 B]; chunk ownership (q, q+8), physical chunk = logical^(row&7):
// writes and reads both span all 8 bank-quads uniformly (conflict-free).
__global__ __launch_bounds__(512, 4) void fused_mfma(const unsigned short* __restrict__ xb,
                                                     const int2* __restrict__ pairs,
                                                     const unsigned short* __restrict__ Wf,
                                                     float* __restrict__ out) {
    __shared__ unsigned char Alds[2][BM * 256];     // 32 KiB
    const int tid  = threadIdx.x;
    const int nb   = blockIdx.x * BM;
    const int wave = tid >> 6, lane = tid & 63;
    const int lr   = lane & 15, lg = lane >> 4;
    const char* xbc = (const char*)xb;

    // staging: thread t owns row t>>3, logical chunks q and q+8 (q = t&7)
    const int srow = tid >> 3;
    const int q16  = (tid & 7) * 16;
    const int arow = nb + srow;
    const int prow = (arow < N_NODES) ? arow * NET : -1;
    const int sa0  = srow * 256 + ((q16 >> 4) ^ (srow & 7)) * 16;   // physical chunk q^(r&7)
    const int sa1  = sa0 + 128;                                     // physical chunk +8

    uint4v g0[3][2], g1[3][2];   // 3 gather sets in flight
    short8 bfr[2][4];            // B double buffer

#define GLOAD(SET, PV) { \
    int2 p_ = (PV); \
    if (p_.x >= 0) { \
        const char* b0_ = xbc + ((size_t)p_.x << 8); \
        const char* b1_ = xbc + ((size_t)p_.y << 8); \
        g0[SET][0] = *(const uint4v*)(b0_ + q16); \
        g0[SET][1] = *(const uint4v*)(b0_ + 128 + q16); \
        g1[SET][0] = *(const uint4v*)(b1_ + q16); \
        g1[SET][1] = *(const uint4v*)(b1_ + 128 + q16); \
    } else { \
        uint4v z_ = {0u, 0u, 0u, 0u}; \
        g0[SET][0] = z_; g0[SET][1] = z_; g1[SET][0] = z_; g1[SET][1] = z_; } }

#define COMBINE(SET, BUF) { \
    uint4v v0_ = sumpack4(g0[SET][0], g1[SET][0]); \
    uint4v v1_ = sumpack4(g0[SET][1], g1[SET][1]); \
    *(uint4v*)(&Alds[BUF][sa0]) = v0_; \
    *(uint4v*)(&Alds[BUF][sa1]) = v1_; }

// B slice for this wave (cols wave*16..+15), frag-major Wf (verified)
#define LOADB(DST, ET) { _Pragma("unroll") \
    for (int ks_ = 0; ks_ < 4; ks_++) \
        (DST)[ks_] = *(const short8*)(Wf \
            + (size_t)((((ET) * 8 + wave) * 4 + ks_) * 512) + lane * 8); }

#define BARRIER() { \
    asm volatile("s_waitcnt lgkmcnt(0)" ::: "memory"); \
    __builtin_amdgcn_s_barrier(); \
    __builtin_amdgcn_sched_barrier(0); }

    f32x4 acc[4];
#pragma unroll
    for (int i = 0; i < 4; i++) acc[i] = (f32x4)0.f;

    // all 7 slot pairs for this row up front (1-2 cache lines)
    int2 pj[7];
#pragma unroll
    for (int j = 0; j < 7; j++)
        pj[j] = (prow >= 0) ? pairs[prow + j] : make_int2(-1, -1);

    // prologue: sets 0/1/2 <- et 0/1/2; B(0); combine et0 -> buf0; refill set0 <- et3
    GLOAD(0, pj[0])
    GLOAD(1, pj[1])
    GLOAD(2, pj[2])
    LOADB(bfr[0], 0)
    COMBINE(0, 0)          // waits set0 only (one-time L3-latency stall)
    GLOAD(0, pj[3])
    BARRIER()

#pragma unroll
    for (int et = 0; et < NET; ++et) {
        const int cur = et & 1;

        // 1) B for et+1 FIRST (oldest VMEM entry -> its wait never drains gathers)
        if (et + 1 < NET) LOADB(bfr[cur ^ 1], et + 1)

        // 2) gathers for et+3 into set[et%3] (consumed 2 iterations later)
        if (et >= 1 && et + 3 < NET) GLOAD(et % 3, pj[et + 3])

        // 3) combine et+1 (set issued >=2 iters ago; vmcnt wait ~free) -> buf[cur^1]
        if (et + 1 < NET) COMBINE((et + 1) % 3, cur ^ 1)

        // 4) MFMA(et): 4 ks x { 4 ds_read_b128, 4 mfma }, B from regs
#pragma unroll
        for (int ks = 0; ks < 4; ks++) {
            const int coff = (((ks * 4 + lg) ^ (lr & 7)) << 4);
            short8 b_ = bfr[cur][ks];
#pragma unroll
            for (int fm = 0; fm < 4; fm++) {
                short8 a_ = *(const short8*)(&Alds[cur][(fm * 16 + lr) * 256 + coff]);
                acc[fm] = __builtin_amdgcn_mfma_f32_16x16x32_bf16(a_, b_, acc[fm], 0, 0, 0);
            }
        }

        // 5) lgkmcnt-only barrier (gathers stay in flight)
        if (et + 1 < NET) BARRIER()
    }

    // epilogue: D layout col=lane&15, row=(lane>>4)*4+reg (verified)
#pragma unroll
    for (int fm = 0; fm < 4; fm++) {
        int row0 = nb + fm * 16 + lg * 4;
        int colo = wave * 16 + lr;
#pragma unroll
        for (int j = 0; j < 4; j++)
            if (row0 + j < N_NODES)
                out[(size_t)(row0 + j) * C + colo] = acc[fm][j];
    }
#undef GLOAD
#undef COMBINE
#undef LOADB
#undef BARRIER
}

extern "C" void kernel_launch(void* const* d_in, const int* in_sizes, int n_in,
                              void* d_out, int out_size, void* d_ws, size_t ws_size,
                              hipStream_t stream) {
    const float* x   = (const float*)d_in[0];
    const int*   col = (const int*)d_in[1];
    const int*   idx = (const int*)d_in[2];
    const float* W   = (const float*)d_in[3];
    float* out = (float*)d_out;

    int2* pairs        = (int2*)d_ws;                               // 5.6 MB
    unsigned short* xb = (unsigned short*)((char*)pairs + (size_t)S_SLOTS * 8);  // 25.6 MB
    unsigned short* Wf = xb + (size_t)N_NODES * C;                  // 229 KB

    prep1<<<NB_CVTX + NB_CVTW + NB_INIT, 256, 0, stream>>>(x, W, xb, Wf, pairs);
    prep2<<<(E_EDGES + 255) / 256, 256, 0, stream>>>(idx, col, pairs);
    fused_mfma<<<(N_NODES + BM - 1) / BM, 512, 0, stream>>>(xb, pairs, Wf, out);
}